// Round 1
// baseline (375.467 us; speedup 1.0000x reference)
//
#include <hip/hip_runtime.h>

#define POOL 7
#define HH 100
#define WW 100
#define CC 512

typedef float vfloat4 __attribute__((ext_vector_type(4)));

// One block per output cell (b, r, py, px); 128 threads x float4 = 512 channels.
// 1-D grid with bijective XCD swizzle: hardware round-robins consecutive
// blockIdx.x across the 8 XCDs, so with chunk = nblocks/8 = R*49, XCD k owns
// the contiguous original range [k*chunk, (k+1)*chunk) == ALL cells of batch
// b==k.  Per-XCD L2 working set: one 20.5 MB input slab (was: all 164 MB),
// and the 49 corner-sharing cells of each ROI hit the SAME L2.
__global__ __launch_bounds__(128) void roi_pool_kernel(
    const float* __restrict__ x, const int* __restrict__ rois,
    float* __restrict__ out, int R, int chunk)
{
    const int gid = blockIdx.x;
    // chunk==0 -> identity mapping (fallback when nblocks % 8 != 0)
    const int o = chunk ? ((gid & 7) * chunk + (gid >> 3)) : gid;

    const int cell = o % (POOL * POOL);   // py*7+px
    const int rb   = o / (POOL * POOL);
    const int r    = rb % R;
    const int b    = rb / R;

    const int px = cell % POOL;
    const int py = cell / POOL;

    // roi = (x1, y1, w, h)
    const int4 roi = ((const int4*)rois)[r];
    const int rx1 = roi.x, ry1 = roi.y, rw = roi.z, rh = roi.w;

    // y axis coords (match numpy fp32 order: (i+0.5)*(sz/7)-0.5, clip, floor)
    float szy = (float)rh;
    float vy = ((float)py + 0.5f) * (szy / (float)POOL) - 0.5f;
    vy = fminf(fmaxf(vy, 0.0f), szy - 1.0f);
    int   ylo = (int)floorf(vy);
    float fy  = vy - (float)ylo;
    int   yhi = min(ylo + 1, rh - 1);
    int gy0 = ry1 + ylo, gy1 = ry1 + yhi;

    // x axis coords
    float szx = (float)rw;
    float vx = ((float)px + 0.5f) * (szx / (float)POOL) - 0.5f;
    vx = fminf(fmaxf(vx, 0.0f), szx - 1.0f);
    int   xlo = (int)floorf(vx);
    float fx  = vx - (float)xlo;
    int   xhi = min(xlo + 1, rw - 1);
    int gx0 = rx1 + xlo, gx1 = rx1 + xhi;

    const bool need_x = (fx != 0.0f);   // block-uniform -> no divergence
    const bool need_y = (fy != 0.0f);

    const size_t base = (size_t)b * HH * WW * CC;
    const vfloat4* ptl  = (const vfloat4*)(x + base + ((size_t)gy0 * WW + gx0) * CC);
    const vfloat4* ptr_ = (const vfloat4*)(x + base + ((size_t)gy0 * WW + gx1) * CC);
    const vfloat4* pbl  = (const vfloat4*)(x + base + ((size_t)gy1 * WW + gx0) * CC);
    const vfloat4* pbr  = (const vfloat4*)(x + base + ((size_t)gy1 * WW + gx1) * CC);

    // o is exactly the linear output cell index: out offset = o * CC
    vfloat4* po = (vfloat4*)(out + (size_t)o * CC);

    const int c = threadIdx.x;  // 0..127, 4 channels each (512 total)
    vfloat4 tl = ptl[c];
    vfloat4 tr = tl, bl = tl, br = tl;
    if (need_x) tr = ptr_[c];
    if (need_y) {
        bl = pbl[c];
        br = bl;
        if (need_x) br = pbr[c];
    }

    vfloat4 top = tl + (tr - tl) * fx;
    vfloat4 bot = bl + (br - bl) * fx;
    vfloat4 o4  = top + (bot - top) * fy;

    // output is never re-read: nontemporal store keeps L2/L3 free for input
    __builtin_nontemporal_store(o4, po + c);
}

extern "C" void kernel_launch(void* const* d_in, const int* in_sizes, int n_in,
                              void* d_out, int out_size, void* d_ws, size_t ws_size,
                              hipStream_t stream) {
    const float* x   = (const float*)d_in[0];
    const int* rois  = (const int*)d_in[1];
    float* out       = (float*)d_out;

    const int R = in_sizes[1] / 4;                     // 300
    const int B = in_sizes[0] / (HH * WW * CC);        // 8

    const int nblocks = B * R * POOL * POOL;           // 117600 (divisible by 8)
    const int chunk   = (nblocks & 7) ? 0 : (nblocks >> 3);  // R*49 per XCD

    roi_pool_kernel<<<dim3(nblocks), dim3(128), 0, stream>>>(x, rois, out, R, chunk);
}